// Round 10
// baseline (269.285 us; speedup 1.0000x reference)
//
#include <hip/hip_runtime.h>
#include <hip/hip_bf16.h>
#include <float.h>

// Problem constants (B,H,W,D,K) = (16,32,32,256,8192)
#define NROWS 16384
#define DDIM  256
#define KCB   8192
#define ZQ_ELEMS 4194304

// ws layout (4.3 MB; R1-proven)
#define WS_ESQ_OFF   0                      // float[8192]
#define WS_ZSQ_OFF   32768                  // float[16384]
#define WS_CAND_OFF  98304                  // u32[16384*64] = 4 MB
#define WS_PART_OFF  (98304 + 4194304)      // float[4096]

#define QWINDOW 410   // rescore window: 0.025 in 1/16384 fixed-point quanta

typedef __attribute__((ext_vector_type(8))) short short8;
typedef __attribute__((ext_vector_type(4))) float floatx4;

__device__ __forceinline__ unsigned short bf16_rn(float f) {
    unsigned u = __float_as_uint(f);
    return (unsigned short)((u + 0x7FFFu + ((u >> 16) & 1u)) >> 16);
}

// async global->LDS DMA, 16 B per lane; LDS dest = wave-uniform base + lane*16
__device__ __forceinline__ void gload_lds16(const void* g, void* l) {
    __builtin_amdgcn_global_load_lds(
        (const __attribute__((address_space(1))) void*)(uintptr_t)g,
        (__attribute__((address_space(3))) void*)(unsigned)(uintptr_t)l, 16, 0, 0);
}

// ---------- prep: bf16 convert + numpy-pairwise sumsq (bit-exact, proven r3) ----
__global__ __launch_bounds__(256) void prep_kernel(
    const float* __restrict__ z, const float* __restrict__ cb,
    unsigned short* __restrict__ z16, unsigned short* __restrict__ cb16,
    float* __restrict__ esq, float* __restrict__ zsq) {
#pragma clang fp contract(off)
    int tid = threadIdx.x;
    int rowb = tid >> 2, sub = tid & 3;
    int b = sub >> 1, jq = sub & 1;
    int row = blockIdx.x * 64 + rowb;
    const float* src; unsigned short* dst; float* o;
    if (row < KCB) { src = cb + (size_t)row * DDIM; dst = cb16 + (size_t)row * DDIM; o = esq + row; }
    else { int r = row - KCB; src = z + (size_t)r * DDIM; dst = z16 + (size_t)r * DDIM; o = zsq + r; }
    float r0 = 0.f, r1 = 0.f, r2 = 0.f, r3 = 0.f;
#pragma unroll
    for (int t = 0; t < 16; ++t) {
        int off = b * 128 + t * 8 + jq * 4;
        float4 v = *(const float4*)(src + off);
        float q0 = v.x * v.x, q1 = v.y * v.y, q2 = v.z * v.z, q3 = v.w * v.w;
        r0 = r0 + q0; r1 = r1 + q1; r2 = r2 + q2; r3 = r3 + q3;
        ushort4 w;
        w.x = bf16_rn(v.x); w.y = bf16_rn(v.y); w.z = bf16_rn(v.z); w.w = bf16_rn(v.w);
        *(ushort4*)(dst + off) = w;
    }
    float s = (r0 + r1) + (r2 + r3);
    s = s + __shfl_xor(s, 1);   // jq pair
    s = s + __shfl_xor(s, 2);   // block pair
    if (sub == 0) *o = s;
}

// ---------- bf16 MFMA filter: block = 256 z-rows x 256 cols, 8 waves ----------
// R0-R9 all ~114-121us: every pipe 25-45% busy, sum ~= wall/0.75 -> balanced-
// bound. This version cuts TOTAL pipe work instead of rescheduling it:
//  * 256-row blocks: B-DMA 1.07GB->268MB, L2 total 1.2->0.54GB; LDS reads
//    2.6->1.57GB (wave = 64r x 128c, acc 128/lane).
//  * A staged full-K in 128KB LDS (R0's exact granule-XOR layout, rows
//    generalized to 256); B in ONE 16KB chunk [128c][64K] (R0's exact layout),
//    8 chunks sequential, single-buffered (R4: schedule is not the constraint).
//  * SWAPPED MFMA operands: mfma(bf, af) -> D-col = z-row, so per-row top-2
//    over cb-cols is mostly IN-LANE (32 inserts) + 2-stage q-shuffle, replacing
//    the 4-stage 16-lane shuffles. Same products, same K order -> same scores.
//  * Panels 256 cols -> top-2 per 256 = 64 cand/row (safer; R1-proven resolve).
__global__ __launch_bounds__(512, 2) void gemm_filter_kernel(
    const unsigned short* __restrict__ z16, const unsigned short* __restrict__ cb16,
    const float* __restrict__ esq, unsigned* __restrict__ cand) {
    __shared__ unsigned short As[256 * 256];    // 128 KB, full K
    __shared__ unsigned short Bs[128 * 64];     // 16 KB, one (ct,kt) chunk
    __shared__ unsigned st[256][2][2];          // 4 KB cross-wave top-2 merge

    // ---- XCD-aware bijective block swizzle (nwg=2048 % 8 == 0) ----
    const unsigned flat = blockIdx.x + gridDim.x * blockIdx.y;
    const unsigned xcd = flat & 7u;
    const unsigned idx = (xcd << 8) + (flat >> 3);   // xcd*256 + flat/8
    const int bx = (int)(idx >> 6);                  // col-panel 0..31 (4 per XCD)
    const int by = (int)(idx & 63u);                 // row-block 0..63

    const int tid = threadIdx.x;
    const int w = tid >> 6, lane = tid & 63;
    const int rg = w >> 1, cg = w & 1;          // wave = rows rg*64+, cols cg*64 per chunk
    const int c = lane & 15, q = lane >> 4;
    const int m0 = by * 256;
    const int nbase = bx * 256;

    // ---- prologue: A tile 256x256 via DMA (16 ops/thread-wave), R0 layout ----
#pragma unroll
    for (int p = 0; p < 16; ++p) {
        int s = (w * 16 + p) * 64 + lane;       // 0..8191
        int row = s >> 5, jp = s & 31;          // row 0..255, slot 0..31
        int j = (jp & 24) | ((jp & 7) ^ (row & 7));   // source-addr XOR swizzle
        gload_lds16(z16 + (size_t)(m0 + row) * 256 + j * 8,
                    (char*)As + (w * 16 + p) * 1024);
    }

    floatx4 acc[2][4][4];   // [ct][f][nf] — 128 regs; D[cbcol][zrow] (swapped)
#pragma unroll
    for (int ct = 0; ct < 2; ++ct)
#pragma unroll
        for (int f = 0; f < 4; ++f)
#pragma unroll
            for (int nf = 0; nf < 4; ++nf) acc[ct][f][nf] = (floatx4){0.f, 0.f, 0.f, 0.f};

    short8 af[4][2];   // [f][ks] for current kt (read when ct==0)

#pragma unroll
    for (int chunk = 0; chunk < 8; ++chunk) {
        const int kt = chunk >> 1, ct = chunk & 1;
        if (chunk) __syncthreads();   // prior chunk's Bs reads complete
#pragma unroll
        for (int p = 0; p < 2; ++p) {   // stage B chunk [128c][64K], R0 layout
            int s = (w * 2 + p) * 64 + lane;    // 0..1023
            int col = s >> 3, jp = s & 7;
            int j = jp ^ (col & 7);
            gload_lds16(cb16 + (size_t)(nbase + ct * 128 + col) * 256 + kt * 64 + j * 8,
                        (char*)Bs + (w * 2 + p) * 1024);
        }
        __syncthreads();   // DMA drained (compiler emits vmcnt(0) before barrier)
        if (ct == 0) {     // A-frags for this kt (reused across both ct)
#pragma unroll
            for (int f = 0; f < 4; ++f)
#pragma unroll
                for (int ks = 0; ks < 2; ++ks) {
                    int row = rg * 64 + f * 16 + c;
                    af[f][ks] = *(const short8*)((const char*)As + row * 512 +
                                 (kt * 8 + (((ks * 4 + q)) ^ (row & 7))) * 16);
                }
        }
        short8 bf[4][2];
#pragma unroll
        for (int nf = 0; nf < 4; ++nf)
#pragma unroll
            for (int ks = 0; ks < 2; ++ks) {
                int col = cg * 64 + nf * 16 + c;
                bf[nf][ks] = *(const short8*)((const char*)Bs + col * 128 +
                              (((ks * 4 + q) ^ (col & 7))) * 16);
            }
#pragma unroll
        for (int f = 0; f < 4; ++f)
#pragma unroll
            for (int nf = 0; nf < 4; ++nf) {
                // SWAPPED: first operand = cb frag -> D-row = cbcol, D-col = zrow
                acc[ct][f][nf] = __builtin_amdgcn_mfma_f32_16x16x32_bf16(
                    bf[nf][0], af[f][0], acc[ct][f][nf], 0, 0, 0);
                acc[ct][f][nf] = __builtin_amdgcn_mfma_f32_16x16x32_bf16(
                    bf[nf][1], af[f][1], acc[ct][f][nf], 0, 0, 0);
            }
    }

    // ---- epilogue: per-lane values are D[cbcol = ..+q*4+r][zrow = f*16+c] ----
    // ekq hoisted (independent of f): 32 loads once per block
    float ekq[2][4][4];
#pragma unroll
    for (int ct = 0; ct < 2; ++ct)
#pragma unroll
        for (int nf = 0; nf < 4; ++nf)
#pragma unroll
            for (int r = 0; r < 4; ++r) {
                int col = nbase + ct * 128 + cg * 64 + nf * 16 + q * 4 + r;
                ekq[ct][nf][r] = (esq[col] + 8.0f) * 16384.0f;   // key+8 in quanta
            }
#pragma unroll
    for (int f = 0; f < 4; ++f) {
        unsigned b1 = 0xFFFFFFFFu, b2 = 0xFFFFFFFFu;
#pragma unroll
        for (int ct = 0; ct < 2; ++ct)
#pragma unroll
            for (int nf = 0; nf < 4; ++nf)
#pragma unroll
                for (int r = 0; r < 4; ++r) {
                    int col = nbase + ct * 128 + cg * 64 + nf * 16 + q * 4 + r;
                    float fx = fmaf(-32768.0f, acc[ct][f][nf][r], ekq[ct][nf][r]);
                    unsigned p = ((unsigned)fx << 13) | (unsigned)col;
                    unsigned nb2;   // top-2 insert: b2 = med3(p,b1,b2); b1 = min
                    asm("v_med3_u32 %0, %1, %2, %3"
                        : "=v"(nb2) : "v"(p), "v"(b1), "v"(b2));
                    b2 = nb2;
                    b1 = min(b1, p);
                }
        // reduce across q (lanes +-16, +-32) — 2 stages
        unsigned x1 = b1, x2 = b2;
#pragma unroll
        for (int sft = 16; sft < 64; sft <<= 1) {
            unsigned o1 = __shfl_xor(x1, sft);
            unsigned o2 = __shfl_xor(x2, sft);
            unsigned mx = max(x1, o1);
            x1 = min(x1, o1);
            x2 = min(min(mx, x2), o2);
        }
        if (q == 0) {
            st[rg * 64 + f * 16 + c][cg][0] = x1;
            st[rg * 64 + f * 16 + c][cg][1] = x2;
        }
    }
    __syncthreads();
    if (tid < 256) {   // merge the 2 col-group halves; write 2 cand per row
        unsigned a1 = st[tid][0][0], a2 = st[tid][0][1];
        unsigned p1 = st[tid][1][0], p2 = st[tid][1][1];
        unsigned mx = max(a1, p1);
        a1 = min(a1, p1);
        a2 = min(min(mx, a2), p2);
        cand[(size_t)(m0 + tid) * 64 + bx * 2 + 0] = a1;
        cand[(size_t)(m0 + tid) * 64 + bx * 2 + 1] = a2;
    }
}

// ---------- resolve (numpy-replica fp32 rescore, R1-proven 64-cand) + gather --
__global__ __launch_bounds__(256) void resolve_gather_kernel(
    const float* __restrict__ z, const float* __restrict__ cb,
    const float* __restrict__ zsq, const float* __restrict__ esq,
    const unsigned* __restrict__ cand, float* __restrict__ out,
    float* __restrict__ partials) {
#pragma clang fp contract(off)
    __shared__ float wls[4];
    int w = threadIdx.x >> 6, l = threadIdx.x & 63;
    int row = blockIdx.x * 4 + w;
    unsigned p = cand[(size_t)row * 64 + l];    // 64 candidates/row, one per lane
    unsigned m = p;
#pragma unroll
    for (int s = 32; s; s >>= 1) m = min(m, __shfl_xor(m, s));
    bool active = ((p >> 13) <= (m >> 13) + QWINDOW);
    float dref = FLT_MAX; int k = 0x7FFFFFFF;
    if (active) {
        k = (int)(p & 8191u);
        const float* zr = z + (size_t)row * DDIM;
        const float* er = cb + (size_t)k * DDIM;
        float cacc = 0.f;
        // float4 loads; fmaf chain sequence and order IDENTICAL to scalar loop
#pragma unroll 8
        for (int d = 0; d < DDIM; d += 4) {
            float4 zv = *(const float4*)(zr + d);
            float4 ev = *(const float4*)(er + d);
            cacc = fmaf(zv.x, ev.x, cacc);
            cacc = fmaf(zv.y, ev.y, cacc);
            cacc = fmaf(zv.z, ev.z, cacc);
            cacc = fmaf(zv.w, ev.w, cacc);
        }
        float s1 = zsq[row] + esq[k];          // numpy: z_sq + e_sq (fp32 round)
        float two = 2.0f * cacc;               // exact
        dref = s1 - two;                       // single fp32 round
    }
#pragma unroll
    for (int s = 32; s; s >>= 1) {
        float od = __shfl_xor(dref, s);
        int ok = __shfl_xor(k, s);
        if (od < dref || (od == dref && ok < k)) { dref = od; k = ok; }
    }
    if (l == 0) out[ZQ_ELEMS + row] = (float)k;
    float ls = 0.f;
#pragma unroll
    for (int t = 0; t < 4; ++t) {
        int d = l + t * 64;
        float e = cb[(size_t)k * DDIM + d];
        float zv = z[(size_t)row * DDIM + d];
        out[(size_t)row * DDIM + d] = zv + (e - zv);  // z_q_st == z_q numerically
        float df = zv - e;
        ls = fmaf(df, df, ls);
    }
#pragma unroll
    for (int s = 32; s; s >>= 1) ls += __shfl_xor(ls, s);
    if (l == 0) wls[w] = ls;
    __syncthreads();
    if (threadIdx.x == 0)
        partials[blockIdx.x] = (wls[0] + wls[1]) + (wls[2] + wls[3]);
}

__global__ __launch_bounds__(256) void final_kernel(const float* __restrict__ partials,
                                                    float* __restrict__ out) {
    __shared__ double wd[4];
    int w = threadIdx.x >> 6, l = threadIdx.x & 63;
    double s = 0.0;
#pragma unroll
    for (int j = 0; j < 16; ++j) s += (double)partials[threadIdx.x + j * 256];
#pragma unroll
    for (int sh = 32; sh; sh >>= 1) s += __shfl_xor(s, sh);
    if (l == 0) wd[w] = s;
    __syncthreads();
    if (threadIdx.x == 0)
        out[ZQ_ELEMS + NROWS] =
            (float)(1.25 * ((wd[0] + wd[1]) + (wd[2] + wd[3])) / (double)ZQ_ELEMS);
}

extern "C" void kernel_launch(void* const* d_in, const int* in_sizes, int n_in,
                              void* d_out, int out_size, void* d_ws, size_t ws_size,
                              hipStream_t stream) {
    const float* z = (const float*)d_in[0];
    const float* cb = (const float*)d_in[1];
    float* out = (float*)d_out;
    char* ws = (char*)d_ws;
    float* esq = (float*)(ws + WS_ESQ_OFF);
    float* zsq = (float*)(ws + WS_ZSQ_OFF);
    unsigned* cand = (unsigned*)(ws + WS_CAND_OFF);
    float* partials = (float*)(ws + WS_PART_OFF);
    // bf16 scratch inside d_out (12 MB < 16.8 MB); overwritten by outputs later
    unsigned short* z16 = (unsigned short*)d_out;
    unsigned short* cb16 = z16 + (size_t)NROWS * DDIM;

    prep_kernel<<<dim3((KCB + NROWS) / 64), 256, 0, stream>>>(z, cb, z16, cb16, esq, zsq);
    gemm_filter_kernel<<<dim3(32, NROWS / 256), 512, 0, stream>>>(z16, cb16, esq, cand);
    resolve_gather_kernel<<<dim3(NROWS / 4), 256, 0, stream>>>(z, cb, zsq, esq, cand, out, partials);
    final_kernel<<<1, 256, 0, stream>>>(partials, out);
}